// Round 4
// baseline (1079.579 us; speedup 1.0000x reference)
//
#include <hip/hip_runtime.h>

// Problem constants
#define B_  16
#define C_  256
#define H_  32
#define W_  32
#define O_  256
#define K2_ 9
#define HW_ 1024
#define MPOS 64        // positions per block (2 rows)
#define NTHR 256

// ---------------------------------------------------------------------------
// Fused deformable conv (3x3, pad=1, stride=1) + bias + ReLU.
// One block = one image b, 2 rows (64 positions), all 256 output channels.
// Loop over input channels c: stage plane in LDS, sample 64x9 into LDS,
// stage w[:,c,:] transposed, 8x8 register-blocked outer product.
// ---------------------------------------------------------------------------
__global__ __launch_bounds__(NTHR) void dconv_kernel(
    const float* __restrict__ xin,   // [B,C,H,W]
    const float* __restrict__ off,   // [B,18,H,W]
    const float* __restrict__ wgt,   // [O,C,3,3]
    const float* __restrict__ bias,  // [O]
    float* __restrict__ out)         // [B,O,H,W]
{
    __shared__ float  xs[HW_];            // input plane for channel c
    __shared__ int4   midx[MPOS * K2_];   // 4 gather indices per (pos,tap)
    __shared__ float4 mwgt[MPOS * K2_];   // 4 bilinear weights (masked)
    __shared__ float  samp[K2_][MPOS];    // sampled values, [k][pos]
    __shared__ float  wl[K2_][O_];        // weights for channel c, [k][o]

    const int tid  = threadIdx.x;
    const int blk  = blockIdx.x;
    const int b    = blk >> 4;     // 16 row-pair tiles per image
    const int tile = blk & 15;
    const int yrow = tile * 2;

    // ---- metadata stage (c-independent): 576 items ----
    for (int item = tid; item < MPOS * K2_; item += NTHR) {
        const int pos = item & 63;
        const int k   = item >> 6;
        const int y   = yrow + (pos >> 5);
        const int x   = pos & 31;
        const float dyo = off[((b * 18 + 2 * k)     << 10) + (y << 5) + x];
        const float dxo = off[((b * 18 + 2 * k + 1) << 10) + (y << 5) + x];
        const float yy = dyo + (float)(k / 3 - 1) + (float)y;
        const float xx = dxo + (float)(k % 3 - 1) + (float)x;
        const float fy0 = floorf(yy), fx0 = floorf(xx);
        const float dy = yy - fy0, dx = xx - fx0;
        const int iy0 = (int)fy0, ix0 = (int)fx0;
        const int iy1 = iy0 + 1,  ix1 = ix0 + 1;
        const bool vy0 = (iy0 >= 0) && (iy0 < H_);
        const bool vy1 = (iy1 >= 0) && (iy1 < H_);
        const bool vx0 = (ix0 >= 0) && (ix0 < W_);
        const bool vx1 = (ix1 >= 0) && (ix1 < W_);
        const int cy0 = min(max(iy0, 0), H_ - 1), cy1 = min(max(iy1, 0), H_ - 1);
        const int cx0 = min(max(ix0, 0), W_ - 1), cx1 = min(max(ix1, 0), W_ - 1);
        int4 id; float4 wv;
        id.x = cy0 * W_ + cx0;  wv.x = (vy0 && vx0) ? (1.f - dy) * (1.f - dx) : 0.f;
        id.y = cy0 * W_ + cx1;  wv.y = (vy0 && vx1) ? (1.f - dy) * dx         : 0.f;
        id.z = cy1 * W_ + cx0;  wv.z = (vy1 && vx0) ? dy * (1.f - dx)         : 0.f;
        id.w = cy1 * W_ + cx1;  wv.w = (vy1 && vx1) ? dy * dx                 : 0.f;
        midx[item] = id;
        mwgt[item] = wv;
    }

    // GEMM-stage thread roles: og in [0,32) owns o = og*8..og*8+7,
    // pg in [0,8) owns pos = pg*8..pg*8+7.
    const int og = tid >> 3;
    const int pg = tid & 7;

    float acc[8][8];
    #pragma unroll
    for (int p = 0; p < 8; ++p)
        #pragma unroll
        for (int i = 0; i < 8; ++i) acc[p][i] = 0.f;

    for (int c = 0; c < C_; ++c) {
        __syncthreads();  // previous iter's reads of xs/wl done; midx ready (iter 0)

        // stage input plane (1024 floats, 1 float4/thread)
        ((float4*)xs)[tid] = ((const float4*)(xin + ((size_t)(b * C_ + c) << 10)))[tid];

        // stage weights for channel c, transposed to [k][o]; thread t = o
        {
            const float* wrow = wgt + ((size_t)tid * C_ + c) * K2_;
            float wk[K2_];
            #pragma unroll
            for (int k = 0; k < K2_; ++k) wk[k] = wrow[k];
            #pragma unroll
            for (int k = 0; k < K2_; ++k) wl[k][tid] = wk[k];
        }
        __syncthreads();

        // sampling: 576 values via precomputed metadata
        for (int item = tid; item < MPOS * K2_; item += NTHR) {
            const int4   id = midx[item];
            const float4 wv = mwgt[item];
            ((float*)samp)[item] =
                wv.x * xs[id.x] + wv.y * xs[id.y] + wv.z * xs[id.z] + wv.w * xs[id.w];
        }
        __syncthreads();

        // 8x8 register-blocked outer product over the 9 taps
        #pragma unroll
        for (int k = 0; k < K2_; ++k) {
            float sv[8], wv8[8];
            *(float4*)&sv[0]  = *(const float4*)&samp[k][pg * 8];
            *(float4*)&sv[4]  = *(const float4*)&samp[k][pg * 8 + 4];
            *(float4*)&wv8[0] = *(const float4*)&wl[k][og * 8];
            *(float4*)&wv8[4] = *(const float4*)&wl[k][og * 8 + 4];
            #pragma unroll
            for (int p = 0; p < 8; ++p)
                #pragma unroll
                for (int i = 0; i < 8; ++i)
                    acc[p][i] = fmaf(sv[p], wv8[i], acc[p][i]);
        }
    }

    // epilogue: bias + ReLU, write [B,O,H,W]
    #pragma unroll
    for (int i = 0; i < 8; ++i) {
        const int o  = og * 8 + i;
        const float bb = bias[o];
        #pragma unroll
        for (int p = 0; p < 8; ++p) {
            const int pos = pg * 8 + p;
            const int y = yrow + (pos >> 5);
            const int x = pos & 31;
            out[((size_t)(b * O_ + o) << 10) + (y << 5) + x] = fmaxf(acc[p][i] + bb, 0.f);
        }
    }
}

// ---------------------------------------------------------------------------
// Global average pool: one wave per (b,c) plane.
// ---------------------------------------------------------------------------
__global__ __launch_bounds__(64) void pool_kernel(
    const float* __restrict__ h, float* __restrict__ pooled)
{
    const int bc = blockIdx.x;  // 0..B*C-1
    const int t  = threadIdx.x;
    const float4* p = (const float4*)(h + ((size_t)bc << 10));
    float s = 0.f;
    #pragma unroll
    for (int j = 0; j < 4; ++j) {
        const float4 v = p[t + 64 * j];
        s += v.x + v.y + v.z + v.w;
    }
    #pragma unroll
    for (int o = 32; o > 0; o >>= 1) s += __shfl_down(s, o);
    if (t == 0) pooled[bc] = s * (1.f / 1024.f);
}

// ---------------------------------------------------------------------------
// FC: out[b,n] = pooled[b,:] . fc_w[n,:] + fc_b[n]. One block per image.
// ---------------------------------------------------------------------------
__global__ __launch_bounds__(256) void fc_kernel(
    const float* __restrict__ pooled, const float* __restrict__ fw,
    const float* __restrict__ fb, float* __restrict__ out)
{
    __shared__ float pl[C_];
    const int b = blockIdx.x;
    const int t = threadIdx.x;
    pl[t] = pooled[b * C_ + t];
    __syncthreads();
    for (int n = t; n < 1000; n += 256) {
        const float4* wr = (const float4*)(fw + (size_t)n * C_);
        float s = 0.f;
        #pragma unroll 8
        for (int j = 0; j < C_ / 4; ++j) {
            const float4 v = wr[j];
            s += v.x * pl[4 * j] + v.y * pl[4 * j + 1] +
                 v.z * pl[4 * j + 2] + v.w * pl[4 * j + 3];
        }
        out[b * 1000 + n] = s + fb[n];
    }
}

extern "C" void kernel_launch(void* const* d_in, const int* in_sizes, int n_in,
                              void* d_out, int out_size, void* d_ws, size_t ws_size,
                              hipStream_t stream)
{
    const float* x   = (const float*)d_in[0];
    const float* off = (const float*)d_in[1];
    const float* w1  = (const float*)d_in[2];
    const float* b1  = (const float*)d_in[3];
    const float* w2  = (const float*)d_in[4];
    const float* b2  = (const float*)d_in[5];
    const float* fcw = (const float*)d_in[6];
    const float* fcb = (const float*)d_in[7];
    float* outp = (float*)d_out;

    float* h1     = (float*)d_ws;                       // 16*256*1024 floats
    float* h2     = h1 + (size_t)B_ * O_ * HW_;         // 16*256*1024 floats
    float* pooled = h2 + (size_t)B_ * O_ * HW_;         // 4096 floats

    dconv_kernel<<<B_ * 16, NTHR, 0, stream>>>(x,  off, w1, b1, h1);
    dconv_kernel<<<B_ * 16, NTHR, 0, stream>>>(h1, off, w2, b2, h2);
    pool_kernel<<<B_ * C_, 64, 0, stream>>>(h2, pooled);
    fc_kernel<<<B_, 256, 0, stream>>>(pooled, fcw, fcb, outp);
}

// Round 5
// 453.348 us; speedup vs baseline: 2.3813x; 2.3813x over previous
//
#include <hip/hip_runtime.h>

// Problem constants
#define B_   16
#define C_   256
#define H_   32
#define W_   32
#define O_   256
#define K2_  9
#define HW_  1024
#define KTOT 2304      // 256*9
#define NPOS 16384     // B*H*W

typedef __bf16 bf16;
typedef __attribute__((ext_vector_type(8))) __bf16 bf16x8;
typedef __attribute__((ext_vector_type(4))) float  f32x4;

__device__ __forceinline__ void gload_lds16(const bf16* g, bf16* l) {
    __builtin_amdgcn_global_load_lds(
        (const __attribute__((address_space(1))) void*)g,
        (__attribute__((address_space(3))) void*)l, 16, 0, 0);
}

// ---------------------------------------------------------------------------
// prep_w: w [O][C][3][3] f32  ->  Wmat [O][KTOT] bf16,
// k = cg*288 + tap*32 + cl, where c = cg*32+cl.  (matches sample_kernel chunks)
// ---------------------------------------------------------------------------
__global__ __launch_bounds__(256) void prep_w(
    const float* __restrict__ w, bf16* __restrict__ Wm)
{
    const int o = blockIdx.x;
    for (int k = threadIdx.x; k < KTOT; k += 256) {
        const int cg  = k / 288;
        const int rem = k - cg * 288;
        const int tap = rem >> 5;
        const int cl  = rem & 31;
        const int c   = cg * 32 + cl;
        Wm[(size_t)o * KTOT + k] = (bf16)w[((size_t)o * C_ + c) * K2_ + tap];
    }
}

// ---------------------------------------------------------------------------
// sample_kernel: build S[pos][k] bf16 (im2col with bilinear deform sampling).
// Grid 2048: bx = b*128 + rt*8 + cg  (b image, rt row-pair tile, cg chan group).
// Per block: metadata once; loop 32 channels: stage f32 plane in LDS, sample
// 64pos x 9tap into chunk Sc[64][288]; then coalesced row writes to S.
// src plane for (b,c) at src + b*b_stride + c*c_stride (works for x and F2).
// ---------------------------------------------------------------------------
__global__ __launch_bounds__(256) void sample_kernel(
    const float* __restrict__ src, size_t c_stride, size_t b_stride,
    const float* __restrict__ off,
    bf16* __restrict__ S)
{
    __shared__ int4   midx[576];
    __shared__ float4 mwgt[576];
    __shared__ float  xs[HW_];
    __shared__ bf16   Sc[64][288];

    const int tid = threadIdx.x;
    const int bx  = blockIdx.x;
    const int cg  = bx & 7;
    const int rt  = (bx >> 3) & 15;
    const int b   = bx >> 7;
    const int yrow = rt * 2;

    // ---- metadata: 576 (pos,tap) items, c-independent ----
    for (int item = tid; item < 576; item += 256) {
        const int pos = item & 63;
        const int k   = item >> 6;
        const int y   = yrow + (pos >> 5);
        const int x   = pos & 31;
        const float dyo = off[((b * 18 + 2 * k)     << 10) + (y << 5) + x];
        const float dxo = off[((b * 18 + 2 * k + 1) << 10) + (y << 5) + x];
        const float yy = dyo + (float)(k / 3 - 1) + (float)y;
        const float xx = dxo + (float)(k % 3 - 1) + (float)x;
        const float fy0 = floorf(yy), fx0 = floorf(xx);
        const float dy = yy - fy0, dx = xx - fx0;
        const int iy0 = (int)fy0, ix0 = (int)fx0;
        const int iy1 = iy0 + 1,  ix1 = ix0 + 1;
        const bool vy0 = (iy0 >= 0) && (iy0 < H_);
        const bool vy1 = (iy1 >= 0) && (iy1 < H_);
        const bool vx0 = (ix0 >= 0) && (ix0 < W_);
        const bool vx1 = (ix1 >= 0) && (ix1 < W_);
        const int cy0 = min(max(iy0, 0), H_ - 1), cy1 = min(max(iy1, 0), H_ - 1);
        const int cx0 = min(max(ix0, 0), W_ - 1), cx1 = min(max(ix1, 0), W_ - 1);
        int4 id; float4 wv;
        id.x = cy0 * W_ + cx0;  wv.x = (vy0 && vx0) ? (1.f - dy) * (1.f - dx) : 0.f;
        id.y = cy0 * W_ + cx1;  wv.y = (vy0 && vx1) ? (1.f - dy) * dx         : 0.f;
        id.z = cy1 * W_ + cx0;  wv.z = (vy1 && vx0) ? dy * (1.f - dx)         : 0.f;
        id.w = cy1 * W_ + cx1;  wv.w = (vy1 && vx1) ? dy * dx                 : 0.f;
        midx[item] = id;
        mwgt[item] = wv;
    }

    for (int cl = 0; cl < 32; ++cl) {
        const int c = cg * 32 + cl;
        __syncthreads();   // prev sampling done (and meta ready, iter 0)
        ((float4*)xs)[tid] =
            ((const float4*)(src + b * b_stride + (size_t)c * c_stride))[tid];
        __syncthreads();
        for (int item = tid; item < 576; item += 256) {
            const int pos = item & 63;
            const int k   = item >> 6;
            const int4   id = midx[item];
            const float4 wv = mwgt[item];
            const float s = wv.x * xs[id.x] + wv.y * xs[id.y] +
                            wv.z * xs[id.z] + wv.w * xs[id.w];
            Sc[pos][k * 32 + cl] = (bf16)s;
        }
    }
    __syncthreads();

    // ---- write chunk: 64 rows x 288 bf16 (576B), coalesced-ish ulong copies
    const int r = tid >> 2, q = tid & 3;
    const unsigned long long* sp = (const unsigned long long*)&Sc[r][q * 72];
    unsigned long long* dp = (unsigned long long*)
        (S + ((size_t)(b * 1024 + rt * 64 + r)) * KTOT + cg * 288 + q * 72);
    #pragma unroll
    for (int i = 0; i < 18; ++i) dp[i] = sp[i];
}

// ---------------------------------------------------------------------------
// gemm_kernel: C[o][pos] = Wmat[o][:] . S[pos][:]  (both [*][K] bf16).
// BM=128 (o), BN=64 (pos), BK=64; grid 512 = om(2) x pn(256); 4 waves;
// wave tile 64x32 = 4x2 fragments of 16x16x32 MFMA.
// POOL=false: F[o][pos] = relu(C+bias)  (f32, layer-1 h in F-layout)
// POOL=true : pooled[b*256+o] += sum_pos relu(C+bias)/1024  (layer-2 fused)
// ---------------------------------------------------------------------------
template<bool POOL>
__global__ __launch_bounds__(256) void gemm_kernel(
    const bf16* __restrict__ A,    // Wmat [256][KTOT]
    const bf16* __restrict__ Bm,   // S    [NPOS][KTOT]
    const float* __restrict__ bias,
    float* __restrict__ F,         // !POOL
    float* __restrict__ pooled)    // POOL
{
    __shared__ bf16 Al[128 * 64];
    __shared__ bf16 Bl[64 * 64];

    const int tid  = threadIdx.x;
    const int om   = blockIdx.x >> 8;   // 0..1
    const int pn   = blockIdx.x & 255;  // 0..255
    const int wave = tid >> 6, lane = tid & 63;
    const int wr   = wave >> 1, wc = wave & 1;
    const int l15  = lane & 15, l4 = lane >> 4;

    f32x4 acc[4][2];
    #pragma unroll
    for (int m = 0; m < 4; ++m)
        #pragma unroll
        for (int n = 0; n < 2; ++n) acc[m][n] = (f32x4)0.f;

    for (int kt = 0; kt < KTOT / 64; ++kt) {
        __syncthreads();
        const int k0 = kt * 64;
        // stage A tile: 128 rows x 64 k  (1024 x 16B chunks)
        #pragma unroll
        for (int i = 0; i < 4; ++i) {
            const int flat = i * 256 + tid;
            const int rr = flat >> 3, kk = (flat & 7) << 3;
            gload_lds16(A + (size_t)(om * 128 + rr) * KTOT + k0 + kk,
                        &Al[(i * 256 + wave * 64) * 8]);
        }
        // stage B tile: 64 rows x 64 k  (512 x 16B chunks)
        #pragma unroll
        for (int i = 0; i < 2; ++i) {
            const int flat = i * 256 + tid;
            const int rr = flat >> 3, kk = (flat & 7) << 3;
            gload_lds16(Bm + (size_t)(pn * 64 + rr) * KTOT + k0 + kk,
                        &Bl[(i * 256 + wave * 64) * 8]);
        }
        __syncthreads();   // compiler drains vmcnt before barrier

        #pragma unroll
        for (int ks = 0; ks < 2; ++ks) {
            const int kb = ks * 32 + l4 * 8;
            bf16x8 af[4], bq[2];
            #pragma unroll
            for (int m = 0; m < 4; ++m)
                af[m] = *(const bf16x8*)&Al[(wr * 64 + m * 16 + l15) * 64 + kb];
            #pragma unroll
            for (int n = 0; n < 2; ++n)
                bq[n] = *(const bf16x8*)&Bl[(wc * 32 + n * 16 + l15) * 64 + kb];
            #pragma unroll
            for (int m = 0; m < 4; ++m)
                #pragma unroll
                for (int n = 0; n < 2; ++n)
                    acc[m][n] = __builtin_amdgcn_mfma_f32_16x16x32_bf16(
                        af[m], bq[n], acc[m][n], 0, 0, 0);
        }
    }

    const int obase = om * 128 + wr * 64;
    if (!POOL) {
        #pragma unroll
        for (int m = 0; m < 4; ++m)
            #pragma unroll
            for (int j = 0; j < 4; ++j) {
                const int o  = obase + m * 16 + l4 * 4 + j;
                const float bb = bias[o];
                #pragma unroll
                for (int n = 0; n < 2; ++n) {
                    const int col = pn * 64 + wc * 32 + n * 16 + l15;
                    F[(size_t)o * NPOS + col] = fmaxf(acc[m][n][j] + bb, 0.f);
                }
            }
    } else {
        const int b = pn >> 4;   // pn*64 / 1024
        #pragma unroll
        for (int m = 0; m < 4; ++m)
            #pragma unroll
            for (int j = 0; j < 4; ++j) {
                const int o  = obase + m * 16 + l4 * 4 + j;
                const float bb = bias[o];
                float s = fmaxf(acc[m][0][j] + bb, 0.f) +
                          fmaxf(acc[m][1][j] + bb, 0.f);
                s += __shfl_xor(s, 1);
                s += __shfl_xor(s, 2);
                s += __shfl_xor(s, 4);
                s += __shfl_xor(s, 8);
                if (l15 == 0)
                    atomicAdd(&pooled[b * 256 + o], s * (1.f / 1024.f));
            }
    }
}

// ---------------------------------------------------------------------------
// FC: out[b,n] = pooled[b,:] . fc_w[n,:] + fc_b[n]. One block per image.
// ---------------------------------------------------------------------------
__global__ __launch_bounds__(256) void fc_kernel(
    const float* __restrict__ pooled, const float* __restrict__ fw,
    const float* __restrict__ fb, float* __restrict__ out)
{
    __shared__ float pl[C_];
    const int b = blockIdx.x;
    const int t = threadIdx.x;
    pl[t] = pooled[b * C_ + t];
    __syncthreads();
    for (int n = t; n < 1000; n += 256) {
        const float4* wr = (const float4*)(fw + (size_t)n * C_);
        float s = 0.f;
        #pragma unroll 8
        for (int j = 0; j < C_ / 4; ++j) {
            const float4 v = wr[j];
            s += v.x * pl[4 * j] + v.y * pl[4 * j + 1] +
                 v.z * pl[4 * j + 2] + v.w * pl[4 * j + 3];
        }
        out[b * 1000 + n] = s + fb[n];
    }
}

extern "C" void kernel_launch(void* const* d_in, const int* in_sizes, int n_in,
                              void* d_out, int out_size, void* d_ws, size_t ws_size,
                              hipStream_t stream)
{
    const float* x   = (const float*)d_in[0];
    const float* off = (const float*)d_in[1];
    const float* w1  = (const float*)d_in[2];
    const float* b1  = (const float*)d_in[3];
    const float* w2  = (const float*)d_in[4];
    const float* b2  = (const float*)d_in[5];
    const float* fcw = (const float*)d_in[6];
    const float* fcb = (const float*)d_in[7];
    float* outp = (float*)d_out;

    // workspace layout (all 16B aligned)
    bf16*  S      = (bf16*)d_ws;                       // [NPOS][KTOT]  75.5 MB
    float* F2     = (float*)(S + (size_t)NPOS * KTOT); // [256][NPOS]   16.8 MB
    bf16*  Wm1    = (bf16*)(F2 + (size_t)O_ * NPOS);   // [256][KTOT]    1.2 MB
    bf16*  Wm2    = Wm1 + (size_t)O_ * KTOT;           //                1.2 MB
    float* pooled = (float*)(Wm2 + (size_t)O_ * KTOT); // [16][256]      16 KB

    prep_w<<<O_, 256, 0, stream>>>(w1, Wm1);
    prep_w<<<O_, 256, 0, stream>>>(w2, Wm2);
    hipMemsetAsync(pooled, 0, B_ * O_ * sizeof(float), stream);

    // layer 1: sample from x [b][c][hw] f32
    sample_kernel<<<2048, 256, 0, stream>>>(x, (size_t)HW_, (size_t)C_ * HW_, off, S);
    gemm_kernel<false><<<512, 256, 0, stream>>>(Wm1, S, b1, F2, nullptr);

    // layer 2: sample from F2 [c][b*1024+hw] f32
    sample_kernel<<<2048, 256, 0, stream>>>(F2, (size_t)NPOS, (size_t)HW_, off, S);
    gemm_kernel<true><<<512, 256, 0, stream>>>(Wm2, S, b2, nullptr, pooled);

    fc_kernel<<<B_, 256, 0, stream>>>(pooled, fcw, fcb, outp);
}

// Round 7
// 296.940 us; speedup vs baseline: 3.6357x; 1.5267x over previous
//
#include <hip/hip_runtime.h>

// Problem constants
#define B_   16
#define C_   256
#define H_   32
#define W_   32
#define O_   256
#define K2_  9
#define HW_  1024
#define KTOT 2304      // 256*9
#define NPOS 16384     // B*H*W

typedef __bf16 bf16;
typedef __attribute__((ext_vector_type(8))) __bf16 bf16x8;
typedef __attribute__((ext_vector_type(4))) float  f32x4;

__device__ __forceinline__ void gload_lds16(const bf16* g, bf16* l) {
    __builtin_amdgcn_global_load_lds(
        (const __attribute__((address_space(1))) void*)g,
        (__attribute__((address_space(3))) void*)l, 16, 0, 0);
}

// ---------------------------------------------------------------------------
// prep_w: w [O][C][3][3] f32 -> Wmat [O][KTOT] bf16.
// k-order: k = cg*72 + tap*8 + cl, c = cg*8 + cl  (matches sample_kernel).
// ---------------------------------------------------------------------------
__global__ __launch_bounds__(256) void prep_w(
    const float* __restrict__ w, bf16* __restrict__ Wm)
{
    const int o = blockIdx.x;
    for (int k = threadIdx.x; k < KTOT; k += 256) {
        const int cg  = k / 72;
        const int rem = k - cg * 72;
        const int tap = rem >> 3;
        const int cl  = rem & 7;
        const int c   = cg * 8 + cl;
        Wm[(size_t)o * KTOT + k] = (bf16)w[((size_t)o * C_ + c) * K2_ + tap];
    }
}

// ---------------------------------------------------------------------------
// sample_kernel: build S[pos][k] bf16 (im2col w/ bilinear deform sampling).
// Grid 8192: bx -> cg (8-chan group, 32), rt (row-pair tile, 16), b (16).
// Stage 8 planes in LDS + metadata once; each (pos,tap) item gathers 4
// corners from all 8 planes in registers and does ONE 16B global store.
// No LDS intermediate, 2 barriers total.
// ---------------------------------------------------------------------------
__global__ __launch_bounds__(256) void sample_kernel(
    const float* __restrict__ src, size_t c_stride, size_t b_stride,
    const float* __restrict__ off,
    bf16* __restrict__ S)
{
    __shared__ int4   midx[576];
    __shared__ float4 mwgt[576];
    __shared__ float  xs[8][HW_];

    const int tid = threadIdx.x;
    const int bx  = blockIdx.x;
    const int cg  = bx & 31;
    const int rt  = (bx >> 5) & 15;
    const int b   = bx >> 9;
    const int yrow = rt * 2;

    // ---- metadata: 576 (pos,tap) items, channel-independent ----
    for (int item = tid; item < 576; item += 256) {
        const int pos = item & 63;
        const int k   = item >> 6;
        const int y   = yrow + (pos >> 5);
        const int x   = pos & 31;
        const float dyo = off[((b * 18 + 2 * k)     << 10) + (y << 5) + x];
        const float dxo = off[((b * 18 + 2 * k + 1) << 10) + (y << 5) + x];
        const float yy = dyo + (float)(k / 3 - 1) + (float)y;
        const float xx = dxo + (float)(k % 3 - 1) + (float)x;
        const float fy0 = floorf(yy), fx0 = floorf(xx);
        const float dy = yy - fy0, dx = xx - fx0;
        const int iy0 = (int)fy0, ix0 = (int)fx0;
        const int iy1 = iy0 + 1,  ix1 = ix0 + 1;
        const bool vy0 = (iy0 >= 0) && (iy0 < H_);
        const bool vy1 = (iy1 >= 0) && (iy1 < H_);
        const bool vx0 = (ix0 >= 0) && (ix0 < W_);
        const bool vx1 = (ix1 >= 0) && (ix1 < W_);
        const int cy0 = min(max(iy0, 0), H_ - 1), cy1 = min(max(iy1, 0), H_ - 1);
        const int cx0 = min(max(ix0, 0), W_ - 1), cx1 = min(max(ix1, 0), W_ - 1);
        int4 id; float4 wv;
        id.x = cy0 * W_ + cx0;  wv.x = (vy0 && vx0) ? (1.f - dy) * (1.f - dx) : 0.f;
        id.y = cy0 * W_ + cx1;  wv.y = (vy0 && vx1) ? (1.f - dy) * dx         : 0.f;
        id.z = cy1 * W_ + cx0;  wv.z = (vy1 && vx0) ? dy * (1.f - dx)         : 0.f;
        id.w = cy1 * W_ + cx1;  wv.w = (vy1 && vx1) ? dy * dx                 : 0.f;
        midx[item] = id;
        mwgt[item] = wv;
    }

    // ---- stage 8 planes: channels c = cg*8 .. cg*8+7 ----
    {
        const float* base = src + b * b_stride + (size_t)(cg * 8) * c_stride;
        #pragma unroll
        for (int i = 0; i < 8; ++i) {
            const int idx   = i * 256 + tid;     // float4 index in [0,2048)
            const int plane = idx >> 8;
            const int p4    = idx & 255;
            ((float4*)xs[plane])[p4] =
                ((const float4*)(base + (size_t)plane * c_stride))[p4];
        }
    }
    __syncthreads();

    // ---- sample: each item -> 8 channels -> one 16B store ----
    for (int item = tid; item < 576; item += 256) {
        const int pos = item & 63;
        const int tap = item >> 6;
        const int4   id = midx[item];
        const float4 wv = mwgt[item];
        bf16x8 v;
        #pragma unroll
        for (int p = 0; p < 8; ++p) {
            const float s = wv.x * xs[p][id.x] + wv.y * xs[p][id.y] +
                            wv.z * xs[p][id.z] + wv.w * xs[p][id.w];
            v[p] = (bf16)s;
        }
        *(bf16x8*)(S + (size_t)(b * 1024 + rt * 64 + pos) * KTOT
                     + cg * 72 + tap * 8) = v;
    }
}

// ---------------------------------------------------------------------------
// gemm_kernel: C[o][pos] = Wmat[o][:] . S[pos][:]  (both [*][K] bf16).
// BM=128 (o), BN=64 (pos), BK=64; grid 512 = om(2) x pn(256); 4 waves;
// wave tile 64x32 = 4x2 fragments of 16x16x32 MFMA.
// POOL=false: F[o][pos] = relu(C+bias)  (f32, layer-1 h in F-layout)
// POOL=true : pooled[b*256+o] += sum_pos relu(C+bias)/1024  (layer-2 fused)
// ---------------------------------------------------------------------------
template<bool POOL>
__global__ __launch_bounds__(256) void gemm_kernel(
    const bf16* __restrict__ A,    // Wmat [256][KTOT]
    const bf16* __restrict__ Bm,   // S    [NPOS][KTOT]
    const float* __restrict__ bias,
    float* __restrict__ F,         // !POOL
    float* __restrict__ pooled)    // POOL
{
    __shared__ bf16 Al[128 * 64];
    __shared__ bf16 Bl[64 * 64];

    const int tid  = threadIdx.x;
    const int om   = blockIdx.x >> 8;   // 0..1
    const int pn   = blockIdx.x & 255;  // 0..255
    const int wave = tid >> 6, lane = tid & 63;
    const int wr   = wave >> 1, wc = wave & 1;
    const int l15  = lane & 15, l4 = lane >> 4;

    f32x4 acc[4][2];
    #pragma unroll
    for (int m = 0; m < 4; ++m)
        #pragma unroll
        for (int n = 0; n < 2; ++n) acc[m][n] = (f32x4)0.f;

    for (int kt = 0; kt < KTOT / 64; ++kt) {
        __syncthreads();
        const int k0 = kt * 64;
        // stage A tile: 128 rows x 64 k  (1024 x 16B chunks)
        #pragma unroll
        for (int i = 0; i < 4; ++i) {
            const int flat = i * 256 + tid;
            const int rr = flat >> 3, kk = (flat & 7) << 3;
            gload_lds16(A + (size_t)(om * 128 + rr) * KTOT + k0 + kk,
                        &Al[(i * 256 + wave * 64) * 8]);
        }
        // stage B tile: 64 rows x 64 k  (512 x 16B chunks)
        #pragma unroll
        for (int i = 0; i < 2; ++i) {
            const int flat = i * 256 + tid;
            const int rr = flat >> 3, kk = (flat & 7) << 3;
            gload_lds16(Bm + (size_t)(pn * 64 + rr) * KTOT + k0 + kk,
                        &Bl[(i * 256 + wave * 64) * 8]);
        }
        __syncthreads();   // compiler drains vmcnt before barrier

        #pragma unroll
        for (int ks = 0; ks < 2; ++ks) {
            const int kb = ks * 32 + l4 * 8;
            bf16x8 af[4], bq[2];
            #pragma unroll
            for (int m = 0; m < 4; ++m)
                af[m] = *(const bf16x8*)&Al[(wr * 64 + m * 16 + l15) * 64 + kb];
            #pragma unroll
            for (int n = 0; n < 2; ++n)
                bq[n] = *(const bf16x8*)&Bl[(wc * 32 + n * 16 + l15) * 64 + kb];
            #pragma unroll
            for (int m = 0; m < 4; ++m)
                #pragma unroll
                for (int n = 0; n < 2; ++n)
                    acc[m][n] = __builtin_amdgcn_mfma_f32_16x16x32_bf16(
                        af[m], bq[n], acc[m][n], 0, 0, 0);
        }
    }

    const int obase = om * 128 + wr * 64;
    if (!POOL) {
        #pragma unroll
        for (int m = 0; m < 4; ++m)
            #pragma unroll
            for (int j = 0; j < 4; ++j) {
                const int o  = obase + m * 16 + l4 * 4 + j;
                const float bb = bias[o];
                #pragma unroll
                for (int n = 0; n < 2; ++n) {
                    const int col = pn * 64 + wc * 32 + n * 16 + l15;
                    F[(size_t)o * NPOS + col] = fmaxf(acc[m][n][j] + bb, 0.f);
                }
            }
    } else {
        const int b = pn >> 4;   // pn*64 / 1024
        #pragma unroll
        for (int m = 0; m < 4; ++m)
            #pragma unroll
            for (int j = 0; j < 4; ++j) {
                const int o  = obase + m * 16 + l4 * 4 + j;
                const float bb = bias[o];
                float s = fmaxf(acc[m][0][j] + bb, 0.f) +
                          fmaxf(acc[m][1][j] + bb, 0.f);
                s += __shfl_xor(s, 1);
                s += __shfl_xor(s, 2);
                s += __shfl_xor(s, 4);
                s += __shfl_xor(s, 8);
                if (l15 == 0)
                    atomicAdd(&pooled[b * 256 + o], s * (1.f / 1024.f));
            }
    }
}

// ---------------------------------------------------------------------------
// FC: out[b,n] = pooled[b,:] . fc_w[n,:] + fc_b[n]. One block per image.
// ---------------------------------------------------------------------------
__global__ __launch_bounds__(256) void fc_kernel(
    const float* __restrict__ pooled, const float* __restrict__ fw,
    const float* __restrict__ fb, float* __restrict__ out)
{
    __shared__ float pl[C_];
    const int b = blockIdx.x;
    const int t = threadIdx.x;
    pl[t] = pooled[b * C_ + t];
    __syncthreads();
    for (int n = t; n < 1000; n += 256) {
        const float4* wr = (const float4*)(fw + (size_t)n * C_);
        float s = 0.f;
        #pragma unroll 8
        for (int j = 0; j < C_ / 4; ++j) {
            const float4 v = wr[j];
            s += v.x * pl[4 * j] + v.y * pl[4 * j + 1] +
                 v.z * pl[4 * j + 2] + v.w * pl[4 * j + 3];
        }
        out[b * 1000 + n] = s + fb[n];
    }
}

extern "C" void kernel_launch(void* const* d_in, const int* in_sizes, int n_in,
                              void* d_out, int out_size, void* d_ws, size_t ws_size,
                              hipStream_t stream)
{
    const float* x   = (const float*)d_in[0];
    const float* off = (const float*)d_in[1];
    const float* w1  = (const float*)d_in[2];
    const float* b1  = (const float*)d_in[3];
    const float* w2  = (const float*)d_in[4];
    const float* b2  = (const float*)d_in[5];
    const float* fcw = (const float*)d_in[6];
    const float* fcb = (const float*)d_in[7];
    float* outp = (float*)d_out;

    // workspace layout (all 16B aligned)
    bf16*  S      = (bf16*)d_ws;                       // [NPOS][KTOT]  75.5 MB
    float* F2     = (float*)(S + (size_t)NPOS * KTOT); // [256][NPOS]   16.8 MB
    bf16*  Wm1    = (bf16*)(F2 + (size_t)O_ * NPOS);   // [256][KTOT]    1.2 MB
    bf16*  Wm2    = Wm1 + (size_t)O_ * KTOT;           //                1.2 MB
    float* pooled = (float*)(Wm2 + (size_t)O_ * KTOT); // [16][256]      16 KB

    prep_w<<<O_, 256, 0, stream>>>(w1, Wm1);
    prep_w<<<O_, 256, 0, stream>>>(w2, Wm2);
    hipMemsetAsync(pooled, 0, B_ * O_ * sizeof(float), stream);

    // layer 1: sample from x [b][c][hw] f32
    sample_kernel<<<8192, 256, 0, stream>>>(x, (size_t)HW_, (size_t)C_ * HW_, off, S);
    gemm_kernel<false><<<512, 256, 0, stream>>>(Wm1, S, b1, F2, nullptr);

    // layer 2: sample from F2 [c][b*1024+hw] f32
    sample_kernel<<<8192, 256, 0, stream>>>(F2, (size_t)NPOS, (size_t)HW_, off, S);
    gemm_kernel<true><<<512, 256, 0, stream>>>(Wm2, S, b2, nullptr, pooled);

    fc_kernel<<<B_, 256, 0, stream>>>(pooled, fcw, fcb, outp);
}

// Round 8
// 242.414 us; speedup vs baseline: 4.4535x; 1.2249x over previous
//
#include <hip/hip_runtime.h>

// Problem constants
#define B_   16
#define C_   256
#define H_   32
#define W_   32
#define O_   256
#define K2_  9
#define HW_  1024
#define KTOT 2304      // 256*9
#define NPOS 16384     // B*H*W

typedef __bf16 bf16;
typedef __attribute__((ext_vector_type(8))) __bf16 bf16x8;
typedef __attribute__((ext_vector_type(4))) float  f32x4;

__device__ __forceinline__ void gload_lds16(const bf16* g, bf16* l) {
    __builtin_amdgcn_global_load_lds(
        (const __attribute__((address_space(1))) void*)g,
        (__attribute__((address_space(3))) void*)l, 16, 0, 0);
}

__device__ __forceinline__ float4 load4(const float* p, int t) {
    return ((const float4*)p)[t];
}
__device__ __forceinline__ float4 load4(const bf16* p, int t) {
    const ushort4 u = ((const ushort4*)p)[t];
    float4 f;
    f.x = __uint_as_float((unsigned)u.x << 16);
    f.y = __uint_as_float((unsigned)u.y << 16);
    f.z = __uint_as_float((unsigned)u.z << 16);
    f.w = __uint_as_float((unsigned)u.w << 16);
    return f;
}

// ---------------------------------------------------------------------------
// prep_w: w [O][C][3][3] f32 -> Wmat [O][KTOT] bf16.
// k-order: k = cg*72 + tap*8 + cl, c = cg*8+cl.  16B chunk index = cg*9+tap,
// stored at chunk' = (chunk&~7) | ((chunk^o)&7)  — T2 swizzle baked into the
// global layout so linear global_load_lds + XOR'd ds_read is conflict-free.
// ---------------------------------------------------------------------------
__global__ __launch_bounds__(256) void prep_w(
    const float* __restrict__ w, bf16* __restrict__ Wm)
{
    const int o = blockIdx.x;
    for (int k = threadIdx.x; k < KTOT; k += 256) {
        const int cg  = k / 72;
        const int rem = k - cg * 72;
        const int tap = rem >> 3;
        const int cl  = rem & 7;
        const int c   = cg * 8 + cl;
        const int chunk  = cg * 9 + tap;
        const int chunkp = (chunk & ~7) | ((chunk ^ o) & 7);
        Wm[(size_t)o * KTOT + chunkp * 8 + cl] =
            (bf16)w[((size_t)o * C_ + c) * K2_ + tap];
    }
}

// ---------------------------------------------------------------------------
// sample_kernel: build S[pos][k] bf16 (im2col w/ bilinear deform sampling).
// Grid 8192: bx -> cg (8-chan group, 32), rt (row-pair tile, 16), b (16).
// Planes stored PIXEL-MAJOR in LDS: xs4[h][slot(pix)] = float4 of planes
// h*4..h*4+3 at pix, slot(pix)=pix+(pix>>3) (pad 1 float4 per 8 pixels ->
// conflict-free b128 writes and gathers). Gather = 8 ds_read_b128 per item
// (was 32 ds_read_b32). Store applies the T2 chunk swizzle: chunk^(pos&7).
// ---------------------------------------------------------------------------
template<typename T>
__global__ __launch_bounds__(256) void sample_kernel(
    const T* __restrict__ src, size_t c_stride, size_t b_stride,
    const float* __restrict__ off,
    bf16* __restrict__ S)
{
    __shared__ ushort4 midx[576];          // 4 gather pixel ids (<1024)
    __shared__ float4  mwgt[576];          // 4 masked bilinear weights
    __shared__ float4  xs4[2][1152];       // pixel-major planes, padded

    const int tid = threadIdx.x;
    const int bx  = blockIdx.x;
    const int cg  = bx & 31;
    const int rt  = (bx >> 5) & 15;
    const int b   = bx >> 9;
    const int yrow = rt * 2;

    // ---- metadata: 576 (pos,tap) items, channel-independent ----
    for (int item = tid; item < 576; item += 256) {
        const int pos = item & 63;
        const int k   = item >> 6;
        const int y   = yrow + (pos >> 5);
        const int x   = pos & 31;
        const float dyo = off[((b * 18 + 2 * k)     << 10) + (y << 5) + x];
        const float dxo = off[((b * 18 + 2 * k + 1) << 10) + (y << 5) + x];
        const float yy = dyo + (float)(k / 3 - 1) + (float)y;
        const float xx = dxo + (float)(k % 3 - 1) + (float)x;
        const float fy0 = floorf(yy), fx0 = floorf(xx);
        const float dy = yy - fy0, dx = xx - fx0;
        const int iy0 = (int)fy0, ix0 = (int)fx0;
        const int iy1 = iy0 + 1,  ix1 = ix0 + 1;
        const bool vy0 = (iy0 >= 0) && (iy0 < H_);
        const bool vy1 = (iy1 >= 0) && (iy1 < H_);
        const bool vx0 = (ix0 >= 0) && (ix0 < W_);
        const bool vx1 = (ix1 >= 0) && (ix1 < W_);
        const int cy0 = min(max(iy0, 0), H_ - 1), cy1 = min(max(iy1, 0), H_ - 1);
        const int cx0 = min(max(ix0, 0), W_ - 1), cx1 = min(max(ix1, 0), W_ - 1);
        ushort4 id; float4 wv;
        id.x = (unsigned short)(cy0 * W_ + cx0);
        wv.x = (vy0 && vx0) ? (1.f - dy) * (1.f - dx) : 0.f;
        id.y = (unsigned short)(cy0 * W_ + cx1);
        wv.y = (vy0 && vx1) ? (1.f - dy) * dx         : 0.f;
        id.z = (unsigned short)(cy1 * W_ + cx0);
        wv.z = (vy1 && vx0) ? dy * (1.f - dx)         : 0.f;
        id.w = (unsigned short)(cy1 * W_ + cx1);
        wv.w = (vy1 && vx1) ? dy * dx                 : 0.f;
        midx[item] = id;
        mwgt[item] = wv;
    }

    // ---- stage 8 planes pixel-major (register 4x4 transpose) ----
    #pragma unroll
    for (int h = 0; h < 2; ++h) {
        const T* base = src + b * b_stride + (size_t)(cg * 8 + h * 4) * c_stride;
        const float4 v0 = load4(base,                tid);
        const float4 v1 = load4(base + c_stride,     tid);
        const float4 v2 = load4(base + 2 * c_stride, tid);
        const float4 v3 = load4(base + 3 * c_stride, tid);
        const int p0 = 4 * tid;
        xs4[h][(p0    ) + ((p0    ) >> 3)] = make_float4(v0.x, v1.x, v2.x, v3.x);
        xs4[h][(p0 + 1) + ((p0 + 1) >> 3)] = make_float4(v0.y, v1.y, v2.y, v3.y);
        xs4[h][(p0 + 2) + ((p0 + 2) >> 3)] = make_float4(v0.z, v1.z, v2.z, v3.z);
        xs4[h][(p0 + 3) + ((p0 + 3) >> 3)] = make_float4(v0.w, v1.w, v2.w, v3.w);
    }
    __syncthreads();

    // ---- sample: each item -> 8 channels -> one swizzled 16B store ----
    for (int item = tid; item < 576; item += 256) {
        const int pos = item & 63;
        const int tap = item >> 6;
        const ushort4 id = midx[item];
        const float4  wv = mwgt[item];
        const int s0 = id.x + (id.x >> 3);
        const int s1 = id.y + (id.y >> 3);
        const int s2 = id.z + (id.z >> 3);
        const int s3 = id.w + (id.w >> 3);
        bf16x8 v;
        #pragma unroll
        for (int h = 0; h < 2; ++h) {
            const float4 a = xs4[h][s0], bb = xs4[h][s1];
            const float4 c = xs4[h][s2], d  = xs4[h][s3];
            v[h * 4 + 0] = (bf16)(wv.x * a.x + wv.y * bb.x + wv.z * c.x + wv.w * d.x);
            v[h * 4 + 1] = (bf16)(wv.x * a.y + wv.y * bb.y + wv.z * c.y + wv.w * d.y);
            v[h * 4 + 2] = (bf16)(wv.x * a.z + wv.y * bb.z + wv.z * c.z + wv.w * d.z);
            v[h * 4 + 3] = (bf16)(wv.x * a.w + wv.y * bb.w + wv.z * c.w + wv.w * d.w);
        }
        const int chunk  = cg * 9 + tap;
        const int chunkp = (chunk & ~7) | ((chunk ^ pos) & 7);
        *(bf16x8*)(S + (size_t)(b * 1024 + rt * 64 + pos) * KTOT + chunkp * 8) = v;
    }
}

// ---------------------------------------------------------------------------
// gemm_kernel: C[o][pos] = Wmat[o][:] . S[pos][:]  (both [*][K] bf16, chunk-
// swizzled in global layout). BM=128, BN=64, BK=64; grid 512; 4 waves.
// Frag reads XOR the 16B-chunk index by (row&7) -> conflict-free ds_read_b128.
// POOL=false: F[o][pos] = relu(C+bias)  (bf16)
// POOL=true : pooled[b*256+o] += sum_pos relu(C+bias)/1024
// ---------------------------------------------------------------------------
template<bool POOL>
__global__ __launch_bounds__(256) void gemm_kernel(
    const bf16* __restrict__ A,    // Wmat [256][KTOT] swizzled
    const bf16* __restrict__ Bm,   // S    [NPOS][KTOT] swizzled
    const float* __restrict__ bias,
    bf16* __restrict__ F,          // !POOL
    float* __restrict__ pooled)    // POOL
{
    __shared__ bf16 Al[128 * 64];
    __shared__ bf16 Bl[64 * 64];

    const int tid  = threadIdx.x;
    const int om   = blockIdx.x >> 8;   // 0..1
    const int pn   = blockIdx.x & 255;  // 0..255
    const int wave = tid >> 6, lane = tid & 63;
    const int wr   = wave >> 1, wc = wave & 1;
    const int l15  = lane & 15, l4 = lane >> 4;

    f32x4 acc[4][2];
    #pragma unroll
    for (int m = 0; m < 4; ++m)
        #pragma unroll
        for (int n = 0; n < 2; ++n) acc[m][n] = (f32x4)0.f;

    for (int kt = 0; kt < KTOT / 64; ++kt) {
        __syncthreads();
        const int k0 = kt * 64;
        #pragma unroll
        for (int i = 0; i < 4; ++i) {
            const int flat = i * 256 + tid;
            const int rr = flat >> 3, kk = (flat & 7) << 3;
            gload_lds16(A + (size_t)(om * 128 + rr) * KTOT + k0 + kk,
                        &Al[(i * 256 + wave * 64) * 8]);
        }
        #pragma unroll
        for (int i = 0; i < 2; ++i) {
            const int flat = i * 256 + tid;
            const int rr = flat >> 3, kk = (flat & 7) << 3;
            gload_lds16(Bm + (size_t)(pn * 64 + rr) * KTOT + k0 + kk,
                        &Bl[(i * 256 + wave * 64) * 8]);
        }
        __syncthreads();   // compiler drains vmcnt before barrier

        #pragma unroll
        for (int ks = 0; ks < 2; ++ks) {
            const int cbase = ks * 4 + l4;           // chunk within K-step
            bf16x8 af[4], bq[2];
            #pragma unroll
            for (int m = 0; m < 4; ++m) {
                const int R = wr * 64 + m * 16 + l15;
                af[m] = *(const bf16x8*)&Al[R * 64 + ((cbase ^ R) & 7) * 8];
            }
            #pragma unroll
            for (int n = 0; n < 2; ++n) {
                const int R = wc * 32 + n * 16 + l15;
                bq[n] = *(const bf16x8*)&Bl[R * 64 + ((cbase ^ R) & 7) * 8];
            }
            #pragma unroll
            for (int m = 0; m < 4; ++m)
                #pragma unroll
                for (int n = 0; n < 2; ++n)
                    acc[m][n] = __builtin_amdgcn_mfma_f32_16x16x32_bf16(
                        af[m], bq[n], acc[m][n], 0, 0, 0);
        }
    }

    const int obase = om * 128 + wr * 64;
    if (!POOL) {
        #pragma unroll
        for (int m = 0; m < 4; ++m)
            #pragma unroll
            for (int j = 0; j < 4; ++j) {
                const int o  = obase + m * 16 + l4 * 4 + j;
                const float bb = bias[o];
                #pragma unroll
                for (int n = 0; n < 2; ++n) {
                    const int col = pn * 64 + wc * 32 + n * 16 + l15;
                    F[(size_t)o * NPOS + col] =
                        (bf16)fmaxf(acc[m][n][j] + bb, 0.f);
                }
            }
    } else {
        const int b = pn >> 4;   // pn*64 / 1024
        #pragma unroll
        for (int m = 0; m < 4; ++m)
            #pragma unroll
            for (int j = 0; j < 4; ++j) {
                const int o  = obase + m * 16 + l4 * 4 + j;
                const float bb = bias[o];
                float s = fmaxf(acc[m][0][j] + bb, 0.f) +
                          fmaxf(acc[m][1][j] + bb, 0.f);
                s += __shfl_xor(s, 1);
                s += __shfl_xor(s, 2);
                s += __shfl_xor(s, 4);
                s += __shfl_xor(s, 8);
                if (l15 == 0)
                    atomicAdd(&pooled[b * 256 + o], s * (1.f / 1024.f));
            }
    }
}

// ---------------------------------------------------------------------------
// FC: out[b,n] = pooled[b,:] . fc_w[n,:] + fc_b[n]. 64 blocks = (b, quarter).
// ---------------------------------------------------------------------------
__global__ __launch_bounds__(256) void fc_kernel(
    const float* __restrict__ pooled, const float* __restrict__ fw,
    const float* __restrict__ fb, float* __restrict__ out)
{
    __shared__ float pl[C_];
    const int b = blockIdx.x >> 2;
    const int q = blockIdx.x & 3;
    const int t = threadIdx.x;
    pl[t] = pooled[b * C_ + t];
    __syncthreads();
    const int n = q * 250 + t;
    if (t < 250) {
        const float4* wr = (const float4*)(fw + (size_t)n * C_);
        float s = 0.f;
        #pragma unroll 8
        for (int j = 0; j < C_ / 4; ++j) {
            const float4 v = wr[j];
            s += v.x * pl[4 * j] + v.y * pl[4 * j + 1] +
                 v.z * pl[4 * j + 2] + v.w * pl[4 * j + 3];
        }
        out[b * 1000 + n] = s + fb[n];
    }
}

extern "C" void kernel_launch(void* const* d_in, const int* in_sizes, int n_in,
                              void* d_out, int out_size, void* d_ws, size_t ws_size,
                              hipStream_t stream)
{
    const float* x   = (const float*)d_in[0];
    const float* off = (const float*)d_in[1];
    const float* w1  = (const float*)d_in[2];
    const float* b1  = (const float*)d_in[3];
    const float* w2  = (const float*)d_in[4];
    const float* b2  = (const float*)d_in[5];
    const float* fcw = (const float*)d_in[6];
    const float* fcb = (const float*)d_in[7];
    float* outp = (float*)d_out;

    // workspace layout (all 16B aligned)
    bf16*  S      = (bf16*)d_ws;                       // [NPOS][KTOT]  75.5 MB
    bf16*  F2     = S + (size_t)NPOS * KTOT;           // [256][NPOS]    8.4 MB
    bf16*  Wm1    = F2 + (size_t)O_ * NPOS;            // [256][KTOT]    1.2 MB
    bf16*  Wm2    = Wm1 + (size_t)O_ * KTOT;           //                1.2 MB
    float* pooled = (float*)(Wm2 + (size_t)O_ * KTOT); // [16][256]      16 KB

    prep_w<<<O_, 256, 0, stream>>>(w1, Wm1);
    prep_w<<<O_, 256, 0, stream>>>(w2, Wm2);
    hipMemsetAsync(pooled, 0, B_ * O_ * sizeof(float), stream);

    // layer 1: sample from x [b][c][hw] f32
    sample_kernel<float><<<8192, 256, 0, stream>>>(
        x, (size_t)HW_, (size_t)C_ * HW_, off, S);
    gemm_kernel<false><<<512, 256, 0, stream>>>(Wm1, S, b1, F2, nullptr);

    // layer 2: sample from F2 [c][b*1024+hw] bf16
    sample_kernel<bf16><<<8192, 256, 0, stream>>>(
        F2, (size_t)NPOS, (size_t)HW_, off, S);
    gemm_kernel<true><<<512, 256, 0, stream>>>(Wm2, S, b2, nullptr, pooled);

    fc_kernel<<<B_ * 4, 256, 0, stream>>>(pooled, fcw, fcb, outp);
}

// Round 10
// 207.548 us; speedup vs baseline: 5.2016x; 1.1680x over previous
//
#include <hip/hip_runtime.h>

// Problem constants
#define B_     16
#define C_     256
#define H_     32
#define W_     32
#define O_     256
#define K2_    9
#define HW_    1024
#define KTOT   2304     // 256*9
#define NPOS   16384    // B*H*W
#define NCHUNK 288      // KTOT/8 16B-chunks
#define NT     256      // NPOS/64 pos-tiles

typedef __bf16 bf16;
typedef __attribute__((ext_vector_type(8))) __bf16 bf16x8;
typedef __attribute__((ext_vector_type(4))) float  f32x4;

__device__ __forceinline__ void gload_lds16(const bf16* g, bf16* l) {
    __builtin_amdgcn_global_load_lds(
        (const __attribute__((address_space(1))) void*)g,
        (__attribute__((address_space(3))) void*)l, 16, 0, 0);
}

__device__ __forceinline__ float4 load4(const float* p, int t) {
    return ((const float4*)p)[t];
}
__device__ __forceinline__ float4 load4(const bf16* p, int t) {
    const ushort4 u = ((const ushort4*)p)[t];
    float4 f;
    f.x = __uint_as_float((unsigned)u.x << 16);
    f.y = __uint_as_float((unsigned)u.y << 16);
    f.z = __uint_as_float((unsigned)u.z << 16);
    f.w = __uint_as_float((unsigned)u.w << 16);
    return f;
}

// ---------------------------------------------------------------------------
// prep_w: w [O][C][3][3] f32 -> Wt tiled: Wt[om][chunk][o128][8] bf16.
// k-order: k = cg*72 + tap*8 + cl (c = cg*8+cl); chunk = cg*9+tap in [0,288).
// A-tile (om,kt) = chunks [kt*8,kt*8+8) x 128 o = 16KB LINEAR block.
// ---------------------------------------------------------------------------
__global__ __launch_bounds__(256) void prep_w(
    const float* __restrict__ w, bf16* __restrict__ Wt)
{
    const int o    = blockIdx.x;
    const int om   = o >> 7, o128 = o & 127;
    for (int k = threadIdx.x; k < KTOT; k += 256) {
        const int cg  = k / 72;
        const int rem = k - cg * 72;
        const int tap = rem >> 3;
        const int cl  = rem & 7;
        const int c   = cg * 8 + cl;
        const int chunk = cg * 9 + tap;
        Wt[(((size_t)om * NCHUNK + chunk) * 128 + o128) * 8 + cl] =
            (bf16)w[((size_t)o * C_ + c) * K2_ + tap];
    }
}

// ---------------------------------------------------------------------------
// sample_kernel: build S2[t][chunk][p][8] bf16 (im2col, bilinear deform).
// Grid 2048: bx -> cg (8-chan group, 32), rq (4 rt-tiles each, 4), b (16).
// Planes staged pixel-major ONCE per block: xs4[h][slot(pix)] = float4 of
// planes h*4..h*4+3, slot(pix)=pix+(pix>>3) (bank-spread). Then 4 rt tiles:
// per-item metadata inline in regs (no LDS), 8 ds_read_b128 gather, ONE
// coalesced 16B store (wave = 64 consecutive p of one chunk = 1KB contig).
// ---------------------------------------------------------------------------
template<typename T>
__global__ __launch_bounds__(256) void sample_kernel(
    const T* __restrict__ src, size_t c_stride, size_t b_stride,
    const float* __restrict__ off,
    bf16* __restrict__ S)
{
    __shared__ float4 xs4[2][1152];   // pixel-major planes, padded

    const int tid = threadIdx.x;
    const int cg  = blockIdx.x & 31;
    const int rq  = (blockIdx.x >> 5) & 3;
    const int b   = blockIdx.x >> 7;

    // ---- stage 8 planes pixel-major (register 4x4 transpose), once ----
    #pragma unroll
    for (int h = 0; h < 2; ++h) {
        const T* base = src + b * b_stride + (size_t)(cg * 8 + h * 4) * c_stride;
        const float4 v0 = load4(base,                tid);
        const float4 v1 = load4(base + c_stride,     tid);
        const float4 v2 = load4(base + 2 * c_stride, tid);
        const float4 v3 = load4(base + 3 * c_stride, tid);
        const int p0 = 4 * tid;
        xs4[h][(p0    ) + ((p0    ) >> 3)] = make_float4(v0.x, v1.x, v2.x, v3.x);
        xs4[h][(p0 + 1) + ((p0 + 1) >> 3)] = make_float4(v0.y, v1.y, v2.y, v3.y);
        xs4[h][(p0 + 2) + ((p0 + 2) >> 3)] = make_float4(v0.z, v1.z, v2.z, v3.z);
        xs4[h][(p0 + 3) + ((p0 + 3) >> 3)] = make_float4(v0.w, v1.w, v2.w, v3.w);
    }
    __syncthreads();

    // ---- 4 rt tiles; metadata inline; gather; coalesced store ----
    for (int i = 0; i < 4; ++i) {
        const int rt   = rq * 4 + i;
        const int yrow = rt * 2;
        const int t    = b * 16 + rt;
        for (int item = tid; item < 576; item += 256) {
            const int pos = item & 63;
            const int tap = item >> 6;
            const int y   = yrow + (pos >> 5);
            const int x   = pos & 31;
            const float dyo = off[((b * 18 + 2 * tap)     << 10) + (y << 5) + x];
            const float dxo = off[((b * 18 + 2 * tap + 1) << 10) + (y << 5) + x];
            const float yy = dyo + (float)(tap / 3 - 1) + (float)y;
            const float xx = dxo + (float)(tap % 3 - 1) + (float)x;
            const float fy0 = floorf(yy), fx0 = floorf(xx);
            const float dy = yy - fy0, dx = xx - fx0;
            const int iy0 = (int)fy0, ix0 = (int)fx0;
            const int iy1 = iy0 + 1,  ix1 = ix0 + 1;
            const bool vy0 = (iy0 >= 0) && (iy0 < H_);
            const bool vy1 = (iy1 >= 0) && (iy1 < H_);
            const bool vx0 = (ix0 >= 0) && (ix0 < W_);
            const bool vx1 = (ix1 >= 0) && (ix1 < W_);
            const int cy0 = min(max(iy0, 0), H_ - 1), cy1 = min(max(iy1, 0), H_ - 1);
            const int cx0 = min(max(ix0, 0), W_ - 1), cx1 = min(max(ix1, 0), W_ - 1);
            const int p00 = cy0 * W_ + cx0, p01 = cy0 * W_ + cx1;
            const int p10 = cy1 * W_ + cx0, p11 = cy1 * W_ + cx1;
            const float w00 = (vy0 && vx0) ? (1.f - dy) * (1.f - dx) : 0.f;
            const float w01 = (vy0 && vx1) ? (1.f - dy) * dx         : 0.f;
            const float w10 = (vy1 && vx0) ? dy * (1.f - dx)         : 0.f;
            const float w11 = (vy1 && vx1) ? dy * dx                 : 0.f;
            const int s0 = p00 + (p00 >> 3);
            const int s1 = p01 + (p01 >> 3);
            const int s2 = p10 + (p10 >> 3);
            const int s3 = p11 + (p11 >> 3);
            bf16x8 v;
            #pragma unroll
            for (int h = 0; h < 2; ++h) {
                const float4 a = xs4[h][s0], bb = xs4[h][s1];
                const float4 c = xs4[h][s2], d  = xs4[h][s3];
                v[h * 4 + 0] = (bf16)(w00 * a.x + w01 * bb.x + w10 * c.x + w11 * d.x);
                v[h * 4 + 1] = (bf16)(w00 * a.y + w01 * bb.y + w10 * c.y + w11 * d.y);
                v[h * 4 + 2] = (bf16)(w00 * a.z + w01 * bb.z + w10 * c.z + w11 * d.z);
                v[h * 4 + 3] = (bf16)(w00 * a.w + w01 * bb.w + w10 * c.w + w11 * d.w);
            }
            const int chunk = cg * 9 + tap;
            *(bf16x8*)(S + (((size_t)t * NCHUNK + chunk) * 64 + pos) * 8) = v;
        }
    }
}

// ---------------------------------------------------------------------------
// gemm_kernel: C[o][pos] = Wt . S2 (tiled-linear layouts). BM=128, BN=64,
// BK=64; grid 512 = om(2) x pn(256); 4 waves; wave tile 64x32 = 4x2 frags.
// Staging: A-tile 16KB linear, B-tile 8KB linear (gload_lds16). LDS layout
// [ch][row][8] -> frag reads contiguous per quarter-wave: conflict-free.
// POOL=false: F[o][pos] = relu(C+bias) bf16;  POOL=true: fused avg-pool.
// ---------------------------------------------------------------------------
template<bool POOL>
__global__ __launch_bounds__(256) void gemm_kernel(
    const bf16* __restrict__ A,    // Wt [2][288][128][8]
    const bf16* __restrict__ Bm,   // S2 [256][288][64][8]
    const float* __restrict__ bias,
    bf16* __restrict__ F,          // !POOL
    float* __restrict__ pooled)    // POOL
{
    __shared__ bf16 Al[8192];   // [ch8][o128][cl8]
    __shared__ bf16 Bl[4096];   // [ch8][p64][cl8]

    const int tid  = threadIdx.x;
    const int om   = blockIdx.x >> 8;   // 0..1
    const int pn   = blockIdx.x & 255;  // 0..255
    const int wave = tid >> 6, lane = tid & 63;
    const int wr   = wave >> 1, wc = wave & 1;
    const int l15  = lane & 15, l4 = lane >> 4;

    const bf16* Abase = A  + (size_t)om * NCHUNK * 128 * 8;
    const bf16* Bbase = Bm + (size_t)pn * NCHUNK * 64 * 8;

    f32x4 acc[4][2];
    #pragma unroll
    for (int m = 0; m < 4; ++m)
        #pragma unroll
        for (int n = 0; n < 2; ++n) acc[m][n] = (f32x4)0.f;

    for (int kt = 0; kt < NCHUNK / 8; ++kt) {
        __syncthreads();
        #pragma unroll
        for (int i = 0; i < 4; ++i)
            gload_lds16(Abase + (size_t)kt * 8192 + (i * 256 + tid) * 8,
                        &Al[(i * 256 + wave * 64) * 8]);
        #pragma unroll
        for (int i = 0; i < 2; ++i)
            gload_lds16(Bbase + (size_t)kt * 4096 + (i * 256 + tid) * 8,
                        &Bl[(i * 256 + wave * 64) * 8]);
        __syncthreads();   // compiler drains vmcnt before barrier

        #pragma unroll
        for (int ks = 0; ks < 2; ++ks) {
            const int cb = ks * 4 + l4;          // chunk within K-step
            bf16x8 af[4], bq[2];
            #pragma unroll
            for (int m = 0; m < 4; ++m) {
                const int R = wr * 64 + m * 16 + l15;
                af[m] = *(const bf16x8*)&Al[(cb * 128 + R) * 8];
            }
            #pragma unroll
            for (int n = 0; n < 2; ++n) {
                const int R = wc * 32 + n * 16 + l15;
                bq[n] = *(const bf16x8*)&Bl[(cb * 64 + R) * 8];
            }
            #pragma unroll
            for (int m = 0; m < 4; ++m)
                #pragma unroll
                for (int n = 0; n < 2; ++n)
                    acc[m][n] = __builtin_amdgcn_mfma_f32_16x16x32_bf16(
                        af[m], bq[n], acc[m][n], 0, 0, 0);
        }
    }

    const int obase = om * 128 + wr * 64;
    if (!POOL) {
        #pragma unroll
        for (int m = 0; m < 4; ++m)
            #pragma unroll
            for (int j = 0; j < 4; ++j) {
                const int o  = obase + m * 16 + l4 * 4 + j;
                const float bb = bias[o];
                #pragma unroll
                for (int n = 0; n < 2; ++n) {
                    const int col = pn * 64 + wc * 32 + n * 16 + l15;
                    F[(size_t)o * NPOS + col] =
                        (bf16)fmaxf(acc[m][n][j] + bb, 0.f);
                }
            }
    } else {
        const int b = pn >> 4;   // pn*64 / 1024
        #pragma unroll
        for (int m = 0; m < 4; ++m)
            #pragma unroll
            for (int j = 0; j < 4; ++j) {
                const int o  = obase + m * 16 + l4 * 4 + j;
                const float bb = bias[o];
                float s = fmaxf(acc[m][0][j] + bb, 0.f) +
                          fmaxf(acc[m][1][j] + bb, 0.f);
                s += __shfl_xor(s, 1);
                s += __shfl_xor(s, 2);
                s += __shfl_xor(s, 4);
                s += __shfl_xor(s, 8);
                if (l15 == 0)
                    atomicAdd(&pooled[b * 256 + o], s * (1.f / 1024.f));
            }
    }
}

// ---------------------------------------------------------------------------
// FC: out[b,n] = pooled[b,:] . fc_w[n,:] + fc_b[n]. 64 blocks = (b, quarter).
// ---------------------------------------------------------------------------
__global__ __launch_bounds__(256) void fc_kernel(
    const float* __restrict__ pooled, const float* __restrict__ fw,
    const float* __restrict__ fb, float* __restrict__ out)
{
    __shared__ float pl[C_];
    const int b = blockIdx.x >> 2;
    const int q = blockIdx.x & 3;
    const int t = threadIdx.x;
    pl[t] = pooled[b * C_ + t];
    __syncthreads();
    const int n = q * 250 + t;
    if (t < 250) {
        const float4* wr = (const float4*)(fw + (size_t)n * C_);
        float s = 0.f;
        #pragma unroll 8
        for (int j = 0; j < C_ / 4; ++j) {
            const float4 v = wr[j];
            s += v.x * pl[4 * j] + v.y * pl[4 * j + 1] +
                 v.z * pl[4 * j + 2] + v.w * pl[4 * j + 3];
        }
        out[b * 1000 + n] = s + fb[n];
    }
}

extern "C" void kernel_launch(void* const* d_in, const int* in_sizes, int n_in,
                              void* d_out, int out_size, void* d_ws, size_t ws_size,
                              hipStream_t stream)
{
    const float* x   = (const float*)d_in[0];
    const float* off = (const float*)d_in[1];
    const float* w1  = (const float*)d_in[2];
    const float* b1  = (const float*)d_in[3];
    const float* w2  = (const float*)d_in[4];
    const float* b2  = (const float*)d_in[5];
    const float* fcw = (const float*)d_in[6];
    const float* fcb = (const float*)d_in[7];
    float* outp = (float*)d_out;

    // workspace layout (all 16B aligned)
    bf16*  S      = (bf16*)d_ws;                       // [256][288][64][8] 75.5MB
    bf16*  F2     = S + (size_t)NPOS * KTOT;           // [256][NPOS]        8.4MB
    bf16*  Wt1    = F2 + (size_t)O_ * NPOS;            // [2][288][128][8]   1.2MB
    bf16*  Wt2    = Wt1 + (size_t)O_ * KTOT;           //                    1.2MB
    float* pooled = (float*)(Wt2 + (size_t)O_ * KTOT); // [16][256]          16KB

    prep_w<<<O_, 256, 0, stream>>>(w1, Wt1);
    prep_w<<<O_, 256, 0, stream>>>(w2, Wt2);
    hipMemsetAsync(pooled, 0, B_ * O_ * sizeof(float), stream);

    // layer 1: sample from x [b][c][hw] f32
    sample_kernel<float><<<2048, 256, 0, stream>>>(
        x, (size_t)HW_, (size_t)C_ * HW_, off, S);
    gemm_kernel<false><<<512, 256, 0, stream>>>(Wt1, S, b1, F2, nullptr);

    // layer 2: sample from F2 [c][b*1024+hw] bf16
    sample_kernel<bf16><<<2048, 256, 0, stream>>>(
        F2, (size_t)NPOS, (size_t)HW_, off, S);
    gemm_kernel<true><<<512, 256, 0, stream>>>(Wt2, S, b2, nullptr, pooled);

    fc_kernel<<<B_ * 4, 256, 0, stream>>>(pooled, fcw, fcb, outp);
}